// Round 14
// baseline (211.812 us; speedup 1.0000x reference)
//
#include <hip/hip_runtime.h>
#include <hip/hip_bf16.h>
#include <math.h>

#define NNODES 100000
#define NEDGES 800000
#define HDIM 64
#define CDIM 10
#define NGRAPH 500
#define CAP 24
#define OVFCAP 16384
#define BN_EPS 1e-5f
#define TN 64
#define EBLK 2048
#define NBIN2 49
#define BINCAP2 20480
#define SUBN 512
#define NBLKB 196

typedef __attribute__((ext_vector_type(8))) short short8;
typedef __attribute__((ext_vector_type(4))) float f32x4;

__device__ __forceinline__ float bflo(unsigned u){ return __uint_as_float(u << 16); }
__device__ __forceinline__ float bfhi(unsigned u){ return __uint_as_float(u & 0xFFFF0000u); }
__device__ __forceinline__ unsigned f2bf(float f){
    unsigned u = __float_as_uint(f);
    u += 0x7FFFu + ((u >> 16) & 1u);          // RNE
    return u >> 16;
}

// --- pass A: feat fp32->bf16 + LDS-ranked edge partition into 49 coarse bins -------
__global__ __launch_bounds__(256) void prep_part(
        const float4* __restrict__ F, uint4* __restrict__ B,
        const int* __restrict__ src, const int* __restrict__ dst,
        unsigned* __restrict__ gcur, unsigned* __restrict__ bin_edges,
        unsigned* __restrict__ ovfcnt, int* __restrict__ ovf) {
    __shared__ unsigned hist[64], basev[64], loc[64];
    int t = threadIdx.x, blk = blockIdx.x;
    if (t < 64) { hist[t] = 0; loc[t] = 0; }
    __syncthreads();

    unsigned pk[8]; int bn[8];
    #pragma unroll
    for (int i = 0; i < 8; ++i) {
        int e = blk*EBLK + i*256 + t;
        if (e < NEDGES) {
            int d = dst[e], s = src[e];
            bn[i] = d >> 11;
            pk[i] = ((unsigned)(d & 2047) << 17) | (unsigned)s;
            atomicAdd(&hist[bn[i]], 1u);
        } else bn[i] = -1;
        if (e < NEDGES) {
            float4 a = F[2*(size_t)e], b = F[2*(size_t)e+1];
            uint4 o;
            o.x = f2bf(a.x) | (f2bf(a.y) << 16);
            o.y = f2bf(a.z) | (f2bf(a.w) << 16);
            o.z = f2bf(b.x) | (f2bf(b.y) << 16);
            o.w = f2bf(b.z) | (f2bf(b.w) << 16);
            B[e] = o;
        }
    }
    __syncthreads();
    if (t < 64 && hist[t]) basev[t] = atomicAdd(&gcur[t], hist[t]);
    __syncthreads();
    #pragma unroll
    for (int i = 0; i < 8; ++i) {
        if (bn[i] >= 0) {
            unsigned p = basev[bn[i]] + atomicAdd(&loc[bn[i]], 1u);
            if (p < BINCAP2) bin_edges[(size_t)bn[i]*BINCAP2 + p] = pk[i];
            else {
                unsigned oo = atomicAdd(ovfcnt, 1u);
                if (oo < OVFCAP) {
                    ovf[2*oo]   = (int)(pk[i] & 0x1FFFFu);
                    ovf[2*oo+1] = (bn[i] << 11) | (int)(pk[i] >> 17);
                }
            }
        }
    }
}

// --- pass B: one block per 512-node sub-range; LDS CSR build + full-line stream-out -
__global__ __launch_bounds__(256) void build_csr2(
        const unsigned* __restrict__ gcur, const unsigned* __restrict__ bin_edges,
        unsigned* __restrict__ cnt, int* __restrict__ csr,
        unsigned* __restrict__ ovfcnt, int* __restrict__ ovf) {
    __shared__ unsigned lcnt[SUBN];
    __shared__ __align__(16) int lcsr[SUBN][CAP];
    int b = blockIdx.x, t = threadIdx.x;
    int node0 = b * SUBN;
    int bin = node0 >> 11;
    unsigned q = (unsigned)(node0 >> 9) & 3u;
    for (int i = t; i < SUBN; i += 256) lcnt[i] = 0;
    __syncthreads();
    unsigned ec = gcur[bin]; if (ec > BINCAP2) ec = BINCAP2;
    const unsigned* be = bin_edges + (size_t)bin*BINCAP2;
    for (unsigned i = t; i < ec; i += 256) {
        unsigned u = be[i];
        unsigned dl = u >> 17;
        if ((dl >> 9) == q) {
            unsigned ln = dl & 511u;
            int s = (int)(u & 0x1FFFFu);
            unsigned slot = atomicAdd(&lcnt[ln], 1u);
            if (slot < CAP) lcsr[ln][slot] = s;
            else {
                unsigned oo = atomicAdd(ovfcnt, 1u);
                if (oo < OVFCAP) { ovf[2*oo] = s; ovf[2*oo+1] = node0 + (int)ln; }
            }
        }
    }
    __syncthreads();
    for (int i = t; i < SUBN; i += 256) {
        int node = node0 + i;
        if (node < NNODES) cnt[node] = lcnt[i];
    }
    const uint4* ls = (const uint4*)&lcsr[0][0];
    uint4* gs = (uint4*)(csr + (size_t)node0 * CAP);
    for (int i = t; i < SUBN*CAP/4; i += 256) gs[i] = ls[i];
}

// ------ fused layer: bf16 gather -> bf16 LDS -> MFMA GEMM + BN + ELU ----------------
// CLS=true (last layer): also computes logits->entropy in-block (classify fusion).
template<int LAYER, bool CLS>
__global__ __launch_bounds__(512, 4) void layer_fused(
        const unsigned* __restrict__ hb, const unsigned* __restrict__ cnt,
        const int* __restrict__ csr, const unsigned* __restrict__ ovfcnt,
        const int* __restrict__ ovf,
        const float* __restrict__ Ws, const float* __restrict__ bs,
        const float* __restrict__ gammas, const float* __restrict__ betas,
        const float* __restrict__ means, const float* __restrict__ vars_,
        unsigned short* __restrict__ out16,
        const float* __restrict__ Wc, const float* __restrict__ bc,
        float* __restrict__ Hent, unsigned* __restrict__ maxH) {
    __shared__ unsigned short Mb[TN][72];
    __shared__ unsigned short Wt[HDIM][72];
    __shared__ float Scl[HDIM], Shl[HDIM];
    __shared__ unsigned short Bt[16][72];     // Wc^T padded (CLS only)
    __shared__ float bcl[16];
    int tid = threadIdx.x;
    int base = blockIdx.x * TN;

    const float* Wg = Ws + (size_t)LAYER*HDIM*HDIM;
    #pragma unroll
    for (int r = 0; r < 8; ++r) {
        int f = tid + 512*r;                  // f = k*64 + c
        int k = f >> 6, c = f & 63;
        Wt[c][k] = (unsigned short)f2bf(Wg[f]);
    }
    if (tid < HDIM) {
        int c = tid;
        float b  = bs[LAYER*HDIM + c];
        float gm = gammas[LAYER*HDIM + c];
        float be = betas[LAYER*HDIM + c];
        float mu = means[LAYER*HDIM + c];
        float vv = vars_[LAYER*HDIM + c];
        float s  = gm * rsqrtf(vv + BN_EPS);
        Scl[c] = s;
        Shl[c] = (b - mu) * s + be;
    }
    if constexpr (CLS) {
        for (int i = tid; i < 16*64; i += 512) {
            int c = i >> 6, k = i & 63;
            float v = (c < CDIM) ? Wc[k*CDIM + c] : 0.f;
            Bt[c][k] = (unsigned short)f2bf(v);
        }
        if (tid < 16) bcl[tid] = (tid < CDIM) ? bc[tid] : 0.f;
    }

    int row = tid >> 3;
    int sub = tid & 7;
    int node = base + row;
    const uint4* h4 = (const uint4*)hb;
    unsigned novf = *ovfcnt; if (novf > OVFCAP) novf = OVFCAP;
    {
        float a0=0,a1=0,a2=0,a3=0,a4=0,a5=0,a6=0,a7=0;
        if (node < NNODES) {
            unsigned deg = cnt[node]; if (deg > CAP) deg = CAP;
            const int* ed = csr + (size_t)node * CAP;
            unsigned e = 0;
            for (; e + 4 <= deg; e += 4) {
                int4 iv = *(const int4*)(ed + e);
                uint4 v0 = h4[(size_t)iv.x*8 + sub];
                uint4 v1 = h4[(size_t)iv.y*8 + sub];
                uint4 v2 = h4[(size_t)iv.z*8 + sub];
                uint4 v3 = h4[(size_t)iv.w*8 + sub];
                a0 += bflo(v0.x)+bflo(v1.x)+bflo(v2.x)+bflo(v3.x);
                a1 += bfhi(v0.x)+bfhi(v1.x)+bfhi(v2.x)+bfhi(v3.x);
                a2 += bflo(v0.y)+bflo(v1.y)+bflo(v2.y)+bflo(v3.y);
                a3 += bfhi(v0.y)+bfhi(v1.y)+bfhi(v2.y)+bfhi(v3.y);
                a4 += bflo(v0.z)+bflo(v1.z)+bflo(v2.z)+bflo(v3.z);
                a5 += bfhi(v0.z)+bfhi(v1.z)+bfhi(v2.z)+bfhi(v3.z);
                a6 += bflo(v0.w)+bflo(v1.w)+bflo(v2.w)+bflo(v3.w);
                a7 += bfhi(v0.w)+bfhi(v1.w)+bfhi(v2.w)+bfhi(v3.w);
            }
            for (; e < deg; ++e) {
                uint4 v = h4[(size_t)ed[e]*8 + sub];
                a0 += bflo(v.x); a1 += bfhi(v.x);
                a2 += bflo(v.y); a3 += bfhi(v.y);
                a4 += bflo(v.z); a5 += bfhi(v.z);
                a6 += bflo(v.w); a7 += bfhi(v.w);
            }
            if (novf) {
                for (unsigned o = 0; o < novf; ++o) {
                    if (ovf[2*o+1] == node) {
                        uint4 v = h4[(size_t)ovf[2*o]*8 + sub];
                        a0 += bflo(v.x); a1 += bfhi(v.x);
                        a2 += bflo(v.y); a3 += bfhi(v.y);
                        a4 += bflo(v.z); a5 += bfhi(v.z);
                        a6 += bflo(v.w); a7 += bfhi(v.w);
                    }
                }
            }
        }
        uint4 pk;
        pk.x = f2bf(a0) | (f2bf(a1) << 16);
        pk.y = f2bf(a2) | (f2bf(a3) << 16);
        pk.z = f2bf(a4) | (f2bf(a5) << 16);
        pk.w = f2bf(a6) | (f2bf(a7) << 16);
        *(uint4*)&Mb[row][sub*8] = pk;
    }
    __syncthreads();

    int w = tid >> 6;
    if (w < 4) {
        int l  = tid & 63;
        int lr = l & 15;
        int lq = l >> 4;
        short8 a0 = *(const short8*)&Mb[w*16 + lr][lq*8];
        short8 a1 = *(const short8*)&Mb[w*16 + lr][32 + lq*8];
        f32x4 acc0 = {0.f,0.f,0.f,0.f}, acc1 = acc0, acc2 = acc0, acc3 = acc0;
        {
            short8 b0 = *(const short8*)&Wt[ 0 + lr][lq*8];
            short8 b1 = *(const short8*)&Wt[ 0 + lr][32 + lq*8];
            acc0 = __builtin_amdgcn_mfma_f32_16x16x32_bf16(a0, b0, acc0, 0, 0, 0);
            acc0 = __builtin_amdgcn_mfma_f32_16x16x32_bf16(a1, b1, acc0, 0, 0, 0);
        }
        {
            short8 b0 = *(const short8*)&Wt[16 + lr][lq*8];
            short8 b1 = *(const short8*)&Wt[16 + lr][32 + lq*8];
            acc1 = __builtin_amdgcn_mfma_f32_16x16x32_bf16(a0, b0, acc1, 0, 0, 0);
            acc1 = __builtin_amdgcn_mfma_f32_16x16x32_bf16(a1, b1, acc1, 0, 0, 0);
        }
        {
            short8 b0 = *(const short8*)&Wt[32 + lr][lq*8];
            short8 b1 = *(const short8*)&Wt[32 + lr][32 + lq*8];
            acc2 = __builtin_amdgcn_mfma_f32_16x16x32_bf16(a0, b0, acc2, 0, 0, 0);
            acc2 = __builtin_amdgcn_mfma_f32_16x16x32_bf16(a1, b1, acc2, 0, 0, 0);
        }
        {
            short8 b0 = *(const short8*)&Wt[48 + lr][lq*8];
            short8 b1 = *(const short8*)&Wt[48 + lr][32 + lq*8];
            acc3 = __builtin_amdgcn_mfma_f32_16x16x32_bf16(a0, b0, acc3, 0, 0, 0);
            acc3 = __builtin_amdgcn_mfma_f32_16x16x32_bf16(a1, b1, acc3, 0, 0, 0);
        }

        // epilogue: BN + ELU, store bf16 to global (and to Mb when classifying)
        #pragma unroll
        for (int tt = 0; tt < 4; ++tt) {
            f32x4 a = (tt==0)?acc0:(tt==1)?acc1:(tt==2)?acc2:acc3;
            int col = tt*16 + lr;
            float s = Scl[col], sh = Shl[col];
            #pragma unroll
            for (int r = 0; r < 4; ++r) {
                int n2 = base + w*16 + lq*4 + r;
                float y = a[r]*s + sh;
                y = (y > 0.f) ? y : expm1f(y);
                if (n2 < NNODES)
                    out16[(size_t)n2*HDIM + col] = (unsigned short)f2bf(y);
                if constexpr (CLS)
                    Mb[w*16 + lq*4 + r][col] = (unsigned short)f2bf(y);
            }
        }

        if constexpr (CLS) {
            // classify: rows w*16..+15 of Mb (now holding h), 2 MFMAs vs Bt
            int cc = lr;                      // class lane (valid < 10)
            short8 ca0 = *(const short8*)&Mb[w*16 + cc][lq*8];
            short8 ca1 = *(const short8*)&Mb[w*16 + cc][32 + lq*8];
            short8 cb0 = *(const short8*)&Bt[cc][lq*8];
            short8 cb1 = *(const short8*)&Bt[cc][32 + lq*8];
            f32x4 cacc = {0.f,0.f,0.f,0.f};
            cacc = __builtin_amdgcn_mfma_f32_16x16x32_bf16(ca0, cb0, cacc, 0, 0, 0);
            cacc = __builtin_amdgcn_mfma_f32_16x16x32_bf16(ca1, cb1, cacc, 0, 0, 0);

            int n0 = base + w*16 + lq*4;
            float hv[4]; float hvmax = 0.f;
            #pragma unroll
            for (int r = 0; r < 4; ++r) {
                float lg = (cc < CDIM) ? (cacc[r] + bcl[cc]) : -1e30f;
                float mx = lg;
                #pragma unroll
                for (int m = 1; m < 16; m <<= 1) mx = fmaxf(mx, __shfl_xor(mx, m, 64));
                float e  = expf(lg - mx);
                float se = e, dt = e * lg;
                #pragma unroll
                for (int m = 1; m < 16; m <<= 1) {
                    se += __shfl_xor(se, m, 64);
                    dt += __shfl_xor(dt, m, 64);
                }
                float Hv = (mx + logf(se)) - dt/se;
                Hv = fmaxf(Hv, 0.f);
                if (n0 + r >= NNODES) Hv = 0.f;
                hv[r] = Hv;
                hvmax = fmaxf(hvmax, Hv);
            }
            if (cc == 0) {
                if (n0 + 3 < NNODES) {
                    *(float4*)&Hent[n0] = make_float4(hv[0], hv[1], hv[2], hv[3]);
                } else {
                    #pragma unroll
                    for (int r = 0; r < 4; ++r)
                        if (n0 + r < NNODES) Hent[n0 + r] = hv[r];
                }
            }
            #pragma unroll
            for (int m = 16; m < 64; m <<= 1) hvmax = fmaxf(hvmax, __shfl_xor(hvmax, m, 64));
            if (l == 0) atomicMax(maxH, __float_as_uint(hvmax));
        }
    }
}

// ---------------- per-graph lambda-weighted pooling + final classify ----------------
__global__ __launch_bounds__(512) void pool_final_bf16(
        const unsigned* __restrict__ H2, const float* __restrict__ Hent,
        const unsigned* __restrict__ maxH, const int* __restrict__ n2g,
        const float* __restrict__ Wc, const float* __restrict__ bc,
        float* __restrict__ out) {
    __shared__ float partial[16][HDIM];
    __shared__ float pooled[HDIM];
    int g = blockIdx.x;
    int tid = threadIdx.x;

    int lo = 0, hi = NNODES;
    while (lo < hi) { int mid = (lo+hi) >> 1; if (n2g[mid] < g) lo = mid+1; else hi = mid; }
    int start = lo;
    hi = NNODES;
    while (lo < hi) { int mid = (lo+hi) >> 1; if (n2g[mid] < g+1) lo = mid+1; else hi = mid; }
    int end = lo;

    float invMax = 1.0f / __uint_as_float(*maxH);
    int grp = tid >> 5, l = tid & 31;
    float ax = 0.f, ay = 0.f;
    for (int i = start + grp; i < end; i += 16) {
        float lam = 1.0f - Hent[i] * invMax;
        unsigned u = H2[(size_t)i*32 + l];
        ax += lam * bflo(u);
        ay += lam * bfhi(u);
    }
    partial[grp][2*l]   = ax;
    partial[grp][2*l+1] = ay;
    __syncthreads();
    if (tid < HDIM) {
        float s = 0.f;
        #pragma unroll
        for (int hh = 0; hh < 16; ++hh) s += partial[hh][tid];
        pooled[tid] = s;
    }
    __syncthreads();
    if (tid < CDIM) {
        float s = bc[tid];
        for (int k = 0; k < HDIM; ++k) s += pooled[k] * Wc[k*CDIM + tid];
        out[g*CDIM + tid] = s;
    }
}

extern "C" void kernel_launch(void* const* d_in, const int* in_sizes, int n_in,
                              void* d_out, int out_size, void* d_ws, size_t ws_size,
                              hipStream_t stream) {
    const float* feat  = (const float*)d_in[0];
    const int*   src   = (const int*)d_in[1];
    const int*   dst   = (const int*)d_in[2];
    const int*   n2g   = (const int*)d_in[3];
    const float* Ws    = (const float*)d_in[4];
    const float* bs    = (const float*)d_in[5];
    const float* gam   = (const float*)d_in[6];
    const float* bet   = (const float*)d_in[7];
    const float* mea   = (const float*)d_in[8];
    const float* var_  = (const float*)d_in[9];
    const float* Wc    = (const float*)d_in[10];
    const float* bc    = (const float*)d_in[11];
    float* out = (float*)d_out;

    char* ws = (char*)d_ws;
    size_t off = 0;
    auto take = [&](size_t bytes) {
        char* p = ws + off;
        off += (bytes + 255) & ~(size_t)255;
        return p;
    };

    unsigned* gcur     = (unsigned*)take((size_t)64*4);
    unsigned* ovfcnt   = (unsigned*)take(4);
    unsigned* maxH     = (unsigned*)take(4);
    int*      ovf      = (int*)take((size_t)OVFCAP*2*4);
    unsigned* cnt      = (unsigned*)take((size_t)NNODES*4);
    float*    Hent     = (float*)take((size_t)NNODES*4);
    unsigned* featb    = (unsigned*)take((size_t)NNODES*HDIM*2);
    unsigned* HA       = (unsigned*)take((size_t)NNODES*HDIM*2);
    unsigned* HB       = (unsigned*)take((size_t)NNODES*HDIM*2);
    unsigned* bin_edges= (unsigned*)take((size_t)NBIN2*BINCAP2*4);
    int*      csr      = (int*)take((size_t)NBLKB*SUBN*CAP*4);

    hipMemsetAsync(gcur, 0, 64*4, stream);
    hipMemsetAsync(ovfcnt, 0, 4, stream);
    hipMemsetAsync(maxH, 0, 4, stream);

    prep_part<<<(NEDGES + EBLK - 1)/EBLK, 256, 0, stream>>>(
        (const float4*)feat, (uint4*)featb, src, dst, gcur, bin_edges, ovfcnt, ovf);
    build_csr2<<<NBLKB, 256, 0, stream>>>(gcur, bin_edges, cnt, csr, ovfcnt, ovf);

    int grid = (NNODES + TN - 1) / TN;
    layer_fused<0,false><<<grid, 512, 0, stream>>>(featb, cnt, csr, ovfcnt, ovf,
                                             Ws, bs, gam, bet, mea, var_, (unsigned short*)HA,
                                             Wc, bc, Hent, maxH);
    layer_fused<1,false><<<grid, 512, 0, stream>>>((const unsigned*)HA, cnt, csr, ovfcnt, ovf,
                                             Ws, bs, gam, bet, mea, var_, (unsigned short*)HB,
                                             Wc, bc, Hent, maxH);
    layer_fused<2,true><<<grid, 512, 0, stream>>>((const unsigned*)HB, cnt, csr, ovfcnt, ovf,
                                             Ws, bs, gam, bet, mea, var_, (unsigned short*)HA,
                                             Wc, bc, Hent, maxH);

    pool_final_bf16<<<NGRAPH, 512, 0, stream>>>(HA, Hent, maxH, n2g, Wc, bc, out);
}

// Round 15
// 168.152 us; speedup vs baseline: 1.2596x; 1.2596x over previous
//
#include <hip/hip_runtime.h>
#include <hip/hip_bf16.h>
#include <math.h>

#define NNODES 100000
#define NEDGES 800000
#define HDIM 64
#define CDIM 10
#define NGRAPH 500
#define CAP 24
#define OVFCAP 16384
#define BN_EPS 1e-5f
#define TN 64
#define EBLK 2048
#define NBIN2 49
#define BINCAP2 20480
#define SUBN 512
#define NBLKB 196

typedef __attribute__((ext_vector_type(8))) short short8;
typedef __attribute__((ext_vector_type(4))) float f32x4;

__device__ __forceinline__ float bflo(unsigned u){ return __uint_as_float(u << 16); }
__device__ __forceinline__ float bfhi(unsigned u){ return __uint_as_float(u & 0xFFFF0000u); }
__device__ __forceinline__ unsigned f2bf(float f){
    unsigned u = __float_as_uint(f);
    u += 0x7FFFu + ((u >> 16) & 1u);          // RNE
    return u >> 16;
}

// --- pass A: feat fp32->bf16 + LDS-ranked edge partition into 49 coarse bins -------
__global__ __launch_bounds__(256) void prep_part(
        const float4* __restrict__ F, uint4* __restrict__ B,
        const int* __restrict__ src, const int* __restrict__ dst,
        unsigned* __restrict__ gcur, unsigned* __restrict__ bin_edges,
        unsigned* __restrict__ ovfcnt, int* __restrict__ ovf) {
    __shared__ unsigned hist[64], basev[64], loc[64];
    int t = threadIdx.x, blk = blockIdx.x;
    if (t < 64) { hist[t] = 0; loc[t] = 0; }
    __syncthreads();

    unsigned pk[8]; int bn[8];
    #pragma unroll
    for (int i = 0; i < 8; ++i) {
        int e = blk*EBLK + i*256 + t;
        if (e < NEDGES) {
            int d = dst[e], s = src[e];
            bn[i] = d >> 11;
            pk[i] = ((unsigned)(d & 2047) << 17) | (unsigned)s;
            atomicAdd(&hist[bn[i]], 1u);
        } else bn[i] = -1;
        if (e < NEDGES) {
            float4 a = F[2*(size_t)e], b = F[2*(size_t)e+1];
            uint4 o;
            o.x = f2bf(a.x) | (f2bf(a.y) << 16);
            o.y = f2bf(a.z) | (f2bf(a.w) << 16);
            o.z = f2bf(b.x) | (f2bf(b.y) << 16);
            o.w = f2bf(b.z) | (f2bf(b.w) << 16);
            B[e] = o;
        }
    }
    __syncthreads();
    if (t < 64 && hist[t]) basev[t] = atomicAdd(&gcur[t], hist[t]);
    __syncthreads();
    #pragma unroll
    for (int i = 0; i < 8; ++i) {
        if (bn[i] >= 0) {
            unsigned p = basev[bn[i]] + atomicAdd(&loc[bn[i]], 1u);
            if (p < BINCAP2) bin_edges[(size_t)bn[i]*BINCAP2 + p] = pk[i];
            else {
                unsigned oo = atomicAdd(ovfcnt, 1u);
                if (oo < OVFCAP) {
                    ovf[2*oo]   = (int)(pk[i] & 0x1FFFFu);
                    ovf[2*oo+1] = (bn[i] << 11) | (int)(pk[i] >> 17);
                }
            }
        }
    }
}

// --- pass B: one block per 512-node sub-range; LDS CSR build + full-line stream-out -
__global__ __launch_bounds__(256) void build_csr2(
        const unsigned* __restrict__ gcur, const unsigned* __restrict__ bin_edges,
        unsigned* __restrict__ cnt, int* __restrict__ csr,
        unsigned* __restrict__ ovfcnt, int* __restrict__ ovf) {
    __shared__ unsigned lcnt[SUBN];
    __shared__ __align__(16) int lcsr[SUBN][CAP];
    int b = blockIdx.x, t = threadIdx.x;
    int node0 = b * SUBN;
    int bin = node0 >> 11;
    unsigned q = (unsigned)(node0 >> 9) & 3u;
    for (int i = t; i < SUBN; i += 256) lcnt[i] = 0;
    __syncthreads();
    unsigned ec = gcur[bin]; if (ec > BINCAP2) ec = BINCAP2;
    const unsigned* be = bin_edges + (size_t)bin*BINCAP2;
    for (unsigned i = t; i < ec; i += 256) {
        unsigned u = be[i];
        unsigned dl = u >> 17;
        if ((dl >> 9) == q) {
            unsigned ln = dl & 511u;
            int s = (int)(u & 0x1FFFFu);
            unsigned slot = atomicAdd(&lcnt[ln], 1u);
            if (slot < CAP) lcsr[ln][slot] = s;
            else {
                unsigned oo = atomicAdd(ovfcnt, 1u);
                if (oo < OVFCAP) { ovf[2*oo] = s; ovf[2*oo+1] = node0 + (int)ln; }
            }
        }
    }
    __syncthreads();
    for (int i = t; i < SUBN; i += 256) {
        int node = node0 + i;
        if (node < NNODES) cnt[node] = lcnt[i];
    }
    const uint4* ls = (const uint4*)&lcsr[0][0];
    uint4* gs = (uint4*)(csr + (size_t)node0 * CAP);
    for (int i = t; i < SUBN*CAP/4; i += 256) gs[i] = ls[i];
}

// ------ fused layer: bf16 gather -> bf16 LDS -> MFMA 64x64 GEMM + BN + ELU ----------
template<int LAYER>
__global__ __launch_bounds__(512, 8) void layer_fused(
        const unsigned* __restrict__ hb, const unsigned* __restrict__ cnt,
        const int* __restrict__ csr, const unsigned* __restrict__ ovfcnt,
        const int* __restrict__ ovf,
        const float* __restrict__ Ws, const float* __restrict__ bs,
        const float* __restrict__ gammas, const float* __restrict__ betas,
        const float* __restrict__ means, const float* __restrict__ vars_,
        unsigned short* __restrict__ out16) {
    __shared__ unsigned short Mb[TN][72];
    __shared__ unsigned short Wt[HDIM][72];
    __shared__ float Scl[HDIM], Shl[HDIM];
    int tid = threadIdx.x;
    int base = blockIdx.x * TN;

    const float* Wg = Ws + (size_t)LAYER*HDIM*HDIM;
    #pragma unroll
    for (int r = 0; r < 8; ++r) {
        int f = tid + 512*r;                  // f = k*64 + c
        int k = f >> 6, c = f & 63;
        Wt[c][k] = (unsigned short)f2bf(Wg[f]);
    }
    if (tid < HDIM) {
        int c = tid;
        float b  = bs[LAYER*HDIM + c];
        float gm = gammas[LAYER*HDIM + c];
        float be = betas[LAYER*HDIM + c];
        float mu = means[LAYER*HDIM + c];
        float vv = vars_[LAYER*HDIM + c];
        float s  = gm * rsqrtf(vv + BN_EPS);
        Scl[c] = s;
        Shl[c] = (b - mu) * s + be;
    }

    int row = tid >> 3;
    int sub = tid & 7;
    int node = base + row;
    const uint4* h4 = (const uint4*)hb;
    unsigned novf = *ovfcnt; if (novf > OVFCAP) novf = OVFCAP;
    {
        float a0=0,a1=0,a2=0,a3=0,a4=0,a5=0,a6=0,a7=0;
        if (node < NNODES) {
            unsigned deg = cnt[node]; if (deg > CAP) deg = CAP;
            const int* ed = csr + (size_t)node * CAP;
            unsigned e = 0;
            for (; e + 4 <= deg; e += 4) {
                int4 iv = *(const int4*)(ed + e);
                uint4 v0 = h4[(size_t)iv.x*8 + sub];
                uint4 v1 = h4[(size_t)iv.y*8 + sub];
                uint4 v2 = h4[(size_t)iv.z*8 + sub];
                uint4 v3 = h4[(size_t)iv.w*8 + sub];
                a0 += bflo(v0.x)+bflo(v1.x)+bflo(v2.x)+bflo(v3.x);
                a1 += bfhi(v0.x)+bfhi(v1.x)+bfhi(v2.x)+bfhi(v3.x);
                a2 += bflo(v0.y)+bflo(v1.y)+bflo(v2.y)+bflo(v3.y);
                a3 += bfhi(v0.y)+bfhi(v1.y)+bfhi(v2.y)+bfhi(v3.y);
                a4 += bflo(v0.z)+bflo(v1.z)+bflo(v2.z)+bflo(v3.z);
                a5 += bfhi(v0.z)+bfhi(v1.z)+bfhi(v2.z)+bfhi(v3.z);
                a6 += bflo(v0.w)+bflo(v1.w)+bflo(v2.w)+bflo(v3.w);
                a7 += bfhi(v0.w)+bfhi(v1.w)+bfhi(v2.w)+bfhi(v3.w);
            }
            for (; e < deg; ++e) {
                uint4 v = h4[(size_t)ed[e]*8 + sub];
                a0 += bflo(v.x); a1 += bfhi(v.x);
                a2 += bflo(v.y); a3 += bfhi(v.y);
                a4 += bflo(v.z); a5 += bfhi(v.z);
                a6 += bflo(v.w); a7 += bfhi(v.w);
            }
            if (novf) {
                for (unsigned o = 0; o < novf; ++o) {
                    if (ovf[2*o+1] == node) {
                        uint4 v = h4[(size_t)ovf[2*o]*8 + sub];
                        a0 += bflo(v.x); a1 += bfhi(v.x);
                        a2 += bflo(v.y); a3 += bfhi(v.y);
                        a4 += bflo(v.z); a5 += bfhi(v.z);
                        a6 += bflo(v.w); a7 += bfhi(v.w);
                    }
                }
            }
        }
        uint4 pk;
        pk.x = f2bf(a0) | (f2bf(a1) << 16);
        pk.y = f2bf(a2) | (f2bf(a3) << 16);
        pk.z = f2bf(a4) | (f2bf(a5) << 16);
        pk.w = f2bf(a6) | (f2bf(a7) << 16);
        *(uint4*)&Mb[row][sub*8] = pk;
    }
    __syncthreads();

    int w = tid >> 6;
    if (w < 4) {
        int l  = tid & 63;
        int lr = l & 15;
        int lq = l >> 4;
        short8 a0 = *(const short8*)&Mb[w*16 + lr][lq*8];
        short8 a1 = *(const short8*)&Mb[w*16 + lr][32 + lq*8];
        f32x4 acc0 = {0.f,0.f,0.f,0.f}, acc1 = acc0, acc2 = acc0, acc3 = acc0;
        {
            short8 b0 = *(const short8*)&Wt[ 0 + lr][lq*8];
            short8 b1 = *(const short8*)&Wt[ 0 + lr][32 + lq*8];
            acc0 = __builtin_amdgcn_mfma_f32_16x16x32_bf16(a0, b0, acc0, 0, 0, 0);
            acc0 = __builtin_amdgcn_mfma_f32_16x16x32_bf16(a1, b1, acc0, 0, 0, 0);
        }
        {
            short8 b0 = *(const short8*)&Wt[16 + lr][lq*8];
            short8 b1 = *(const short8*)&Wt[16 + lr][32 + lq*8];
            acc1 = __builtin_amdgcn_mfma_f32_16x16x32_bf16(a0, b0, acc1, 0, 0, 0);
            acc1 = __builtin_amdgcn_mfma_f32_16x16x32_bf16(a1, b1, acc1, 0, 0, 0);
        }
        {
            short8 b0 = *(const short8*)&Wt[32 + lr][lq*8];
            short8 b1 = *(const short8*)&Wt[32 + lr][32 + lq*8];
            acc2 = __builtin_amdgcn_mfma_f32_16x16x32_bf16(a0, b0, acc2, 0, 0, 0);
            acc2 = __builtin_amdgcn_mfma_f32_16x16x32_bf16(a1, b1, acc2, 0, 0, 0);
        }
        {
            short8 b0 = *(const short8*)&Wt[48 + lr][lq*8];
            short8 b1 = *(const short8*)&Wt[48 + lr][32 + lq*8];
            acc3 = __builtin_amdgcn_mfma_f32_16x16x32_bf16(a0, b0, acc3, 0, 0, 0);
            acc3 = __builtin_amdgcn_mfma_f32_16x16x32_bf16(a1, b1, acc3, 0, 0, 0);
        }

        #pragma unroll
        for (int tt = 0; tt < 4; ++tt) {
            f32x4 a = (tt==0)?acc0:(tt==1)?acc1:(tt==2)?acc2:acc3;
            int col = tt*16 + lr;
            float s = Scl[col], sh = Shl[col];
            #pragma unroll
            for (int r = 0; r < 4; ++r) {
                int n2 = base + w*16 + lq*4 + r;
                if (n2 < NNODES) {
                    float y = a[r]*s + sh;
                    y = (y > 0.f) ? y : expm1f(y);
                    out16[(size_t)n2*HDIM + col] = (unsigned short)f2bf(y);
                }
            }
        }
    }
}

// ---- classify via MFMA: logits = H @ Wc (K=64), softmax/entropy over 16 lanes ------
__global__ __launch_bounds__(256) void classify_mfma(
        const uint4* __restrict__ h4, const float* __restrict__ Wc,
        const float* __restrict__ bc, float* __restrict__ Hent,
        unsigned* __restrict__ maxH) {
    __shared__ unsigned short Hl[64][72];
    __shared__ unsigned short Bt[16][72];
    __shared__ float wmaxs[4];
    int tid = threadIdx.x;
    int base = blockIdx.x * 64;

    for (int i = tid; i < 16*64; i += 256) {
        int c = i >> 6, k = i & 63;
        float v = (c < CDIM) ? Wc[k*CDIM + c] : 0.f;
        Bt[c][k] = (unsigned short)f2bf(v);
    }
    #pragma unroll
    for (int r = 0; r < 2; ++r) {
        int f = tid + 256*r;
        int row = f >> 3, sub = f & 7;
        uint4 v = make_uint4(0u,0u,0u,0u);
        if (base + row < NNODES) v = h4[(size_t)(base + row)*8 + sub];
        *(uint4*)&Hl[row][sub*8] = v;
    }
    __syncthreads();

    int w  = tid >> 6;
    int l  = tid & 63;
    int cc = l & 15;
    int lq = l >> 4;
    short8 a0 = *(const short8*)&Hl[w*16 + cc][lq*8];
    short8 a1 = *(const short8*)&Hl[w*16 + cc][32 + lq*8];
    short8 b0 = *(const short8*)&Bt[cc][lq*8];
    short8 b1 = *(const short8*)&Bt[cc][32 + lq*8];
    f32x4 acc = {0.f,0.f,0.f,0.f};
    acc = __builtin_amdgcn_mfma_f32_16x16x32_bf16(a0, b0, acc, 0, 0, 0);
    acc = __builtin_amdgcn_mfma_f32_16x16x32_bf16(a1, b1, acc, 0, 0, 0);

    float bcv = (cc < CDIM) ? bc[cc] : 0.f;
    int n0 = base + w*16 + lq*4;
    float hv[4];
    float hvmax = 0.f;
    #pragma unroll
    for (int r = 0; r < 4; ++r) {
        float lg = (cc < CDIM) ? (acc[r] + bcv) : -1e30f;
        float mx = lg;
        #pragma unroll
        for (int m = 1; m < 16; m <<= 1) mx = fmaxf(mx, __shfl_xor(mx, m, 64));
        float e  = expf(lg - mx);
        float se = e, dt = e * lg;
        #pragma unroll
        for (int m = 1; m < 16; m <<= 1) {
            se += __shfl_xor(se, m, 64);
            dt += __shfl_xor(dt, m, 64);
        }
        float Hv = (mx + logf(se)) - dt/se;
        Hv = fmaxf(Hv, 0.f);
        if (n0 + r >= NNODES) Hv = 0.f;
        hv[r] = Hv;
        hvmax = fmaxf(hvmax, Hv);
    }
    if (cc == 0) {
        if (n0 + 3 < NNODES) {
            *(float4*)&Hent[n0] = make_float4(hv[0], hv[1], hv[2], hv[3]);
        } else {
            #pragma unroll
            for (int r = 0; r < 4; ++r)
                if (n0 + r < NNODES) Hent[n0 + r] = hv[r];
        }
    }
    #pragma unroll
    for (int m = 16; m < 64; m <<= 1) hvmax = fmaxf(hvmax, __shfl_xor(hvmax, m, 64));
    if (l == 0) wmaxs[w] = hvmax;
    __syncthreads();
    if (tid == 0) {
        float mm = fmaxf(fmaxf(wmaxs[0], wmaxs[1]), fmaxf(wmaxs[2], wmaxs[3]));
        atomicMax(maxH, __float_as_uint(mm));
    }
}

// ---------------- per-graph lambda-weighted pooling + final classify ----------------
__global__ __launch_bounds__(512) void pool_final_bf16(
        const unsigned* __restrict__ H2, const float* __restrict__ Hent,
        const unsigned* __restrict__ maxH, const int* __restrict__ n2g,
        const float* __restrict__ Wc, const float* __restrict__ bc,
        float* __restrict__ out) {
    __shared__ float partial[16][HDIM];
    __shared__ float pooled[HDIM];
    int g = blockIdx.x;
    int tid = threadIdx.x;

    int lo = 0, hi = NNODES;
    while (lo < hi) { int mid = (lo+hi) >> 1; if (n2g[mid] < g) lo = mid+1; else hi = mid; }
    int start = lo;
    hi = NNODES;
    while (lo < hi) { int mid = (lo+hi) >> 1; if (n2g[mid] < g+1) lo = mid+1; else hi = mid; }
    int end = lo;

    float invMax = 1.0f / __uint_as_float(*maxH);
    int grp = tid >> 5, l = tid & 31;
    float ax = 0.f, ay = 0.f;
    for (int i = start + grp; i < end; i += 16) {
        float lam = 1.0f - Hent[i] * invMax;
        unsigned u = H2[(size_t)i*32 + l];
        ax += lam * bflo(u);
        ay += lam * bfhi(u);
    }
    partial[grp][2*l]   = ax;
    partial[grp][2*l+1] = ay;
    __syncthreads();
    if (tid < HDIM) {
        float s = 0.f;
        #pragma unroll
        for (int hh = 0; hh < 16; ++hh) s += partial[hh][tid];
        pooled[tid] = s;
    }
    __syncthreads();
    if (tid < CDIM) {
        float s = bc[tid];
        for (int k = 0; k < HDIM; ++k) s += pooled[k] * Wc[k*CDIM + tid];
        out[g*CDIM + tid] = s;
    }
}

extern "C" void kernel_launch(void* const* d_in, const int* in_sizes, int n_in,
                              void* d_out, int out_size, void* d_ws, size_t ws_size,
                              hipStream_t stream) {
    const float* feat  = (const float*)d_in[0];
    const int*   src   = (const int*)d_in[1];
    const int*   dst   = (const int*)d_in[2];
    const int*   n2g   = (const int*)d_in[3];
    const float* Ws    = (const float*)d_in[4];
    const float* bs    = (const float*)d_in[5];
    const float* gam   = (const float*)d_in[6];
    const float* bet   = (const float*)d_in[7];
    const float* mea   = (const float*)d_in[8];
    const float* var_  = (const float*)d_in[9];
    const float* Wc    = (const float*)d_in[10];
    const float* bc    = (const float*)d_in[11];
    float* out = (float*)d_out;

    char* ws = (char*)d_ws;
    size_t off = 0;
    auto take = [&](size_t bytes) {
        char* p = ws + off;
        off += (bytes + 255) & ~(size_t)255;
        return p;
    };

    unsigned* gcur     = (unsigned*)take((size_t)64*4);
    unsigned* ovfcnt   = (unsigned*)take(4);
    unsigned* maxH     = (unsigned*)take(4);
    int*      ovf      = (int*)take((size_t)OVFCAP*2*4);
    unsigned* cnt      = (unsigned*)take((size_t)NNODES*4);
    float*    Hent     = (float*)take((size_t)NNODES*4);
    unsigned* featb    = (unsigned*)take((size_t)NNODES*HDIM*2);
    unsigned* HA       = (unsigned*)take((size_t)NNODES*HDIM*2);
    unsigned* HB       = (unsigned*)take((size_t)NNODES*HDIM*2);
    unsigned* bin_edges= (unsigned*)take((size_t)NBIN2*BINCAP2*4);
    int*      csr      = (int*)take((size_t)NBLKB*SUBN*CAP*4);

    hipMemsetAsync(gcur, 0, 64*4, stream);
    hipMemsetAsync(ovfcnt, 0, 4, stream);
    hipMemsetAsync(maxH, 0, 4, stream);

    prep_part<<<(NEDGES + EBLK - 1)/EBLK, 256, 0, stream>>>(
        (const float4*)feat, (uint4*)featb, src, dst, gcur, bin_edges, ovfcnt, ovf);
    build_csr2<<<NBLKB, 256, 0, stream>>>(gcur, bin_edges, cnt, csr, ovfcnt, ovf);

    int grid = (NNODES + TN - 1) / TN;
    layer_fused<0><<<grid, 512, 0, stream>>>(featb, cnt, csr, ovfcnt, ovf,
                                             Ws, bs, gam, bet, mea, var_, (unsigned short*)HA);
    layer_fused<1><<<grid, 512, 0, stream>>>((const unsigned*)HA, cnt, csr, ovfcnt, ovf,
                                             Ws, bs, gam, bet, mea, var_, (unsigned short*)HB);
    layer_fused<2><<<grid, 512, 0, stream>>>((const unsigned*)HB, cnt, csr, ovfcnt, ovf,
                                             Ws, bs, gam, bet, mea, var_, (unsigned short*)HA);

    classify_mfma<<<(NNODES+63)/64, 256, 0, stream>>>((const uint4*)HA, Wc, bc, Hent, maxH);
    pool_final_bf16<<<NGRAPH, 512, 0, stream>>>(HA, Hent, maxH, n2g, Wc, bc, out);
}